// Round 5
// baseline (37888.016 us; speedup 1.0000x reference)
//
#include <hip/hip_runtime.h>
#include <math.h>

#define BSZ   384
#define BM1   383
#define DIM   256
#define NZTOT 768
#define NBLK  128
#define RPB   3
#define TPB   384
#define NITER 100
#define RINGD 8
#define CHB   73728    // chunk bytes: 48 J-rows * 384 cols * 4B
#define NCH   8

// ---- ws layout (float offsets) ----
#define OFF_Z    0          // 768*256
#define OFF_NRM  196608     // 768
#define OFF_K    197376     // 384*768
#define OFF_KP   492288     // 384*384 packed KK
#define OFF_A    639744     // 384*383 final alpha
#define OFF_NUM  786816     // NITER (pad 128)
#define OFF_DEN  786944
#define OFF_ARR  787072
#define OFF_LOSS 787200     // 2 doubles
// total ~3.15 MB

__device__ __forceinline__ void bar() {
    asm volatile("" ::: "memory");
    __builtin_amdgcn_s_barrier();
    asm volatile("" ::: "memory");
}
#define LGKM0() asm volatile("s_waitcnt lgkmcnt(0)" ::: "memory")
#define VM12()  asm volatile("s_waitcnt vmcnt(12)" ::: "memory")
#define VM0()   asm volatile("s_waitcnt vmcnt(0)" ::: "memory")

__device__ __forceinline__ void stage_chunk(const float* __restrict__ KKp, int kc,
                                            char* dstBase, int c) {
    const char* s = (const char*)KKp + (size_t)kc * CHB + (size_t)c * 16;
    char* d = dstBase + c * 16;
    #pragma unroll
    for (int k = 0; k < 12; ++k)
        __builtin_amdgcn_global_load_lds(
            (const __attribute__((address_space(1))) void*)(s + k * 6144),
            (__attribute__((address_space(3))) void*)(d + k * 6144),
            16, 0, 0);
}

__global__ void init_kernel(float* num, float* den, int* arr, double* lossAcc) {
    int t = threadIdx.x;
    if (t < NITER) { num[t] = 0.f; den[t] = 0.f; arr[t] = 0; }
    if (t < 2) lossAcc[t] = 0.0;
}

__global__ void __launch_bounds__(64)
norm_kernel(const float* __restrict__ xis, const float* __restrict__ xjs,
            float* __restrict__ Z, float* __restrict__ nrm2) {
    const int row  = blockIdx.x;
    const int lane = threadIdx.x;
    const float* src = (row < BSZ) ? (xis + (size_t)row * DIM)
                                   : (xjs + (size_t)(row - BSZ) * DIM);
    float4 x = reinterpret_cast<const float4*>(src)[lane];
    float s = x.x*x.x + x.y*x.y + x.z*x.z + x.w*x.w;
    for (int m = 32; m; m >>= 1) s += __shfl_xor(s, m, 64);
    float nrm = sqrtf(s);
    float4 z;
    z.x = x.x / nrm; z.y = x.y / nrm; z.z = x.z / nrm; z.w = x.w / nrm;
    reinterpret_cast<float4*>(Z + (size_t)row * DIM)[lane] = z;
    float s2 = z.x*z.x + z.y*z.y + z.z*z.z + z.w*z.w;
    for (int m = 32; m; m >>= 1) s2 += __shfl_xor(s2, m, 64);
    if (lane == 0) nrm2[row] = s2;
}

__global__ void __launch_bounds__(256)
k_kernel(const float* __restrict__ Z, const float* __restrict__ nrm2,
         float* __restrict__ Km, float* __restrict__ KKp) {
    const int i = blockIdx.x;
    const int j = blockIdx.y * 256 + threadIdx.x;
    __shared__ float zi[DIM];
    zi[threadIdx.x] = Z[(size_t)i * DIM + threadIdx.x];
    __syncthreads();
    const float4* zr = reinterpret_cast<const float4*>(Z + (size_t)j * DIM);
    float acc = 0.f;
    #pragma unroll 8
    for (int k = 0; k < DIM/4; ++k) {
        float4 v = zr[k];
        acc = fmaf(zi[4*k+0], v.x, acc);
        acc = fmaf(zi[4*k+1], v.y, acc);
        acc = fmaf(zi[4*k+2], v.z, acc);
        acc = fmaf(zi[4*k+3], v.w, acc);
    }
    float sq = nrm2[i] + nrm2[j] - 2.f * acc;
    sq = fmaxf(sq, 0.f);
    const float val = expf(-0.1f * sq);
    Km[(size_t)i * NZTOT + j] = val;
    if (j < BSZ) KKp[(size_t)i * BSZ + j] = val;
}

__global__ void __launch_bounds__(TPB, 1)
pgd_kernel(const float* __restrict__ Km, const float* __restrict__ KKp,
           const float* __restrict__ alpha_init,
           float* __restrict__ afin, float* num, float* den, int* arr) {
    const int g    = blockIdx.x;     // 0..127
    const int c    = threadIdx.x;    // column index 0..383
    const int lane = c & 63;
    const int wv   = c >> 6;

    extern __shared__ char dynlds[];          // 2 * 72KB chunk buffers
    char* const bufA = dynlds;
    char* const bufB = dynlds + CHB;

    __shared__ float4 zrow4[RPB][98];         // 392 floats/row (uniform b128 reads)
    __shared__ float  rscr[6][8];
    __shared__ float  rscr2[6];
    __shared__ float  SD[8];                  // 0..2 S_r, 3..5 D_r, 6 den
    __shared__ unsigned long long scanm[2];

    // ---- per-row init (column indexing; diagonal thread c==b is inert) ----
    float a[RPB], p[RPB], kb[RPB];
    int   bb[RPB]; bool vld[RPB];
    #pragma unroll
    for (int r = 0; r < RPB; ++r) {
        const int b = g * RPB + r;
        bb[r]  = b;
        vld[r] = (c != b);
        kb[r]  = Km[(size_t)b * NZTOT + c];
        float v = 0.f;
        if (vld[r]) {
            const int i = c - (c > b ? 1 : 0);
            v = alpha_init[(size_t)b * BM1 + i];
            v = fminf(fmaxf(v, 0.f), 1.f);
        }
        a[r] = v; p[r] = v;
    }
    float hist[RINGD][RPB];
    #pragma unroll
    for (int s = 0; s < RINGD; ++s)
        #pragma unroll
        for (int r = 0; r < RPB; ++r) hist[s][r] = a[r];

    // prologue: 2 chunks in flight
    stage_chunk(KKp, 0, bufA, c);
    stage_chunk(KKp, 1, bufB, c);

    int stopT = -1;

    for (int t = 0; t < NITER; ++t) {
        // ---- phase 1: z, partial reductions ----
        const float beta = (float)t / ((float)t + 3.0f);
        float z[RPB]; float vv[7]; float denp = 0.f;
        #pragma unroll
        for (int r = 0; r < RPB; ++r) {
            const float zr = a[r] + beta * (a[r] - p[r]);   // 0 for diagonal thread
            z[r] = zr;
            ((float*)&zrow4[r][0])[c] = zr;
            vv[r]     = zr;
            vv[3 + r] = kb[r] * zr;
            denp += a[r] * a[r];
        }
        vv[6] = denp;
        #pragma unroll
        for (int k = 0; k < 7; ++k) {
            float x = vv[k];
            x += __shfl_down(x, 32, 64); x += __shfl_down(x, 16, 64);
            x += __shfl_down(x,  8, 64); x += __shfl_down(x,  4, 64);
            x += __shfl_down(x,  2, 64); x += __shfl_down(x,  1, 64);
            if (lane == 0) rscr[wv][k] = x;
        }

        // ---- parallel, spin-free stop scan: thread tau checks iteration tau ----
        int ok = 0;
        if (c < NITER) {
            const int av = __hip_atomic_load(&arr[c], __ATOMIC_ACQUIRE, __HIP_MEMORY_SCOPE_AGENT);
            if (av == NBLK) {
                const float nn = __hip_atomic_load(&num[c], __ATOMIC_RELAXED, __HIP_MEMORY_SCOPE_AGENT);
                const float dd = __hip_atomic_load(&den[c], __ATOMIC_RELAXED, __HIP_MEMORY_SCOPE_AGENT);
                ok = (sqrtf(nn) / (sqrtf(dd) + 1e-8f) < 0.01f) ? 1 : 0;
            }
        }
        {
            const unsigned long long bm = __ballot(ok);
            if (lane == 0 && wv < 2) scanm[wv] = bm;
        }

        LGKM0(); bar();   // B1

        {
            const unsigned long long m0 = scanm[0], m1 = scanm[1];
            const int st = m0 ? (__ffsll(m0) - 1) : (m1 ? 63 + __ffsll(m1) : -1);
            if (st >= 0) { stopT = st; break; }   // uniform; ring depth 8 covers block skew
        }
        if (c < 7) {
            float s = 0.f;
            #pragma unroll
            for (int w = 0; w < 6; ++w) s += rscr[w][c];
            SD[c] = s;
        }

        // ---- phase 2: 8 double-buffered chunks, counted-vmcnt pipeline ----
        float wa[RPB] = {0.f, 0.f, 0.f};
        float wb[RPB] = {0.f, 0.f, 0.f};
        #pragma unroll
        for (int k2 = 0; k2 < NCH; ++k2) {
            VM12();            // stage(k2) done (stage(k2+1)'s 12 still in flight)
            LGKM0();
            bar();             // all waves' portions landed; safe to read buf
            const float* bf = (const float*)((k2 & 1) ? bufB : bufA);
            #pragma unroll
            for (int j4 = 0; j4 < 12; ++j4) {
                const float4 z0 = zrow4[0][k2 * 12 + j4];
                const float4 z1 = zrow4[1][k2 * 12 + j4];
                const float4 z2 = zrow4[2][k2 * 12 + j4];
                const float kA = bf[(j4 * 4 + 0) * 384 + c];
                const float kB = bf[(j4 * 4 + 1) * 384 + c];
                const float kC = bf[(j4 * 4 + 2) * 384 + c];
                const float kD = bf[(j4 * 4 + 3) * 384 + c];
                wa[0] = fmaf(kA, z0.x, wa[0]); wa[1] = fmaf(kA, z1.x, wa[1]); wa[2] = fmaf(kA, z2.x, wa[2]);
                wb[0] = fmaf(kB, z0.y, wb[0]); wb[1] = fmaf(kB, z1.y, wb[1]); wb[2] = fmaf(kB, z2.y, wb[2]);
                wa[0] = fmaf(kC, z0.z, wa[0]); wa[1] = fmaf(kC, z1.z, wa[1]); wa[2] = fmaf(kC, z2.z, wa[2]);
                wb[0] = fmaf(kD, z0.w, wb[0]); wb[1] = fmaf(kD, z1.w, wb[1]); wb[2] = fmaf(kD, z2.w, wb[2]);
            }
            LGKM0();
            bar();             // all waves done reading buf[k2&1]
            stage_chunk(KKp, (k2 + 2) & 7, (k2 & 1) ? bufB : bufA, c);  // K constant: prefetch crosses iterations
        }

        // ---- phase 3: grad, clipped step, reg-ring, num partial ----
        float nump = 0.f;
        const int s = t & (RINGD - 1);
        #pragma unroll
        for (int r = 0; r < RPB; ++r) {
            const float w = wa[r] + wb[r];
            float an = 0.f;
            if (vld[r]) {
                const float grad = SD[r] * (1.f - kb[r]) + 0.1f * z[r] + w - SD[3 + r] - 2.0f;
                an = z[r] - 0.001f * grad;
                an = fminf(fmaxf(an, 0.f), 1.f);
            }
            const float d = an - a[r];
            nump += d * d;
            #pragma unroll
            for (int s2 = 0; s2 < RINGD; ++s2) hist[s2][r] = (s2 == s) ? an : hist[s2][r];
            p[r] = a[r]; a[r] = an;
        }
        {
            float x = nump;
            x += __shfl_down(x, 32, 64); x += __shfl_down(x, 16, 64);
            x += __shfl_down(x,  8, 64); x += __shfl_down(x,  4, 64);
            x += __shfl_down(x,  2, 64); x += __shfl_down(x,  1, 64);
            if (lane == 0) rscr2[wv] = x;
        }
        LGKM0(); bar();   // B3
        if (c == 0) {
            const float nb = rscr2[0] + rscr2[1] + rscr2[2] + rscr2[3] + rscr2[4] + rscr2[5];
            __hip_atomic_fetch_add(&num[t], nb, __ATOMIC_RELAXED, __HIP_MEMORY_SCOPE_AGENT);
            __hip_atomic_fetch_add(&den[t], SD[6], __ATOMIC_RELAXED, __HIP_MEMORY_SCOPE_AGENT);
            __hip_atomic_fetch_add(&arr[t], 1, __ATOMIC_RELEASE, __HIP_MEMORY_SCOPE_AGENT);
        }
    }

    // ---- finalize ----
    float av[RPB];
    #pragma unroll
    for (int r = 0; r < RPB; ++r) av[r] = a[r];
    if (stopT >= 0) {
        const int s = stopT & (RINGD - 1);
        #pragma unroll
        for (int s2 = 0; s2 < RINGD; ++s2)
            #pragma unroll
            for (int r = 0; r < RPB; ++r)
                av[r] = (s2 == s) ? hist[s2][r] : av[r];
    }
    #pragma unroll
    for (int r = 0; r < RPB; ++r) {
        if (vld[r]) {
            const int i = c - (c > bb[r] ? 1 : 0);
            afin[(size_t)bb[r] * BM1 + i] = av[r];
        }
    }
    VM0();   // drain dangling prefetches before endpgm
}

__global__ void __launch_bounds__(TPB)
loss_kernel(const float* __restrict__ Km, const float* __restrict__ afin,
            double* lossAcc) {
    const int b    = blockIdx.x;
    const int tid  = threadIdx.x;
    const int lane = tid & 63;
    const int wv   = tid >> 6;
    __shared__ double dscr[6][2];
    double np = 0.0, pp = 0.0;
    if (tid < BM1) {
        const float ay = afin[(size_t)b * BM1 + tid];
        const int   I  = tid + (tid >= b);
        np = (double)ay * (double)Km[(size_t)I * NZTOT + BSZ + b];
        pp = (double)ay * (double)Km[(size_t)b * NZTOT + BSZ + b];
    }
    for (int o = 32; o; o >>= 1) { np += __shfl_down(np, o, 64); pp += __shfl_down(pp, o, 64); }
    if (lane == 0) { dscr[wv][0] = np; dscr[wv][1] = pp; }
    __syncthreads();
    if (tid == 0) {
        double nb = 0.0, pb = 0.0;
        for (int w = 0; w < 6; ++w) { nb += dscr[w][0]; pb += dscr[w][1]; }
        __hip_atomic_fetch_add(&lossAcc[0], nb, __ATOMIC_RELAXED, __HIP_MEMORY_SCOPE_AGENT);
        __hip_atomic_fetch_add(&lossAcc[1], pb, __ATOMIC_RELAXED, __HIP_MEMORY_SCOPE_AGENT);
    }
}

__global__ void fin_kernel(const double* lossAcc, float* out) {
    out[0] = expf((float)(lossAcc[0] / 384.0 - lossAcc[1] / 384.0));
}

extern "C" void kernel_launch(void* const* d_in, const int* in_sizes, int n_in,
                              void* d_out, int out_size, void* d_ws, size_t ws_size,
                              hipStream_t stream) {
    const float* xis        = (const float*)d_in[0];
    const float* xjs        = (const float*)d_in[1];
    const float* alpha_init = (const float*)d_in[2];
    float* ws   = (float*)d_ws;
    float* Z    = ws + OFF_Z;
    float* nrm2 = ws + OFF_NRM;
    float* Km   = ws + OFF_K;
    float* KKp  = ws + OFF_KP;
    float* afin = ws + OFF_A;
    float* num  = ws + OFF_NUM;
    float* den  = ws + OFF_DEN;
    int*   arr  = (int*)(ws + OFF_ARR);
    double* lossAcc = (double*)(ws + OFF_LOSS);
    float* out  = (float*)d_out;

    // allow 144KB dynamic LDS (idempotent; not a stream op, graph-capture safe)
    hipFuncSetAttribute((const void*)pgd_kernel,
                        hipFuncAttributeMaxDynamicSharedMemorySize, 2 * CHB);

    hipLaunchKernelGGL(init_kernel, dim3(1), dim3(128), 0, stream, num, den, arr, lossAcc);
    hipLaunchKernelGGL(norm_kernel, dim3(NZTOT), dim3(64), 0, stream, xis, xjs, Z, nrm2);
    hipLaunchKernelGGL(k_kernel, dim3(BSZ, 3), dim3(256), 0, stream, Z, nrm2, Km, KKp);
    hipLaunchKernelGGL(pgd_kernel, dim3(NBLK), dim3(TPB), 2 * CHB, stream,
                       Km, KKp, alpha_init, afin, num, den, arr);
    hipLaunchKernelGGL(loss_kernel, dim3(BSZ), dim3(TPB), 0, stream, Km, afin, lossAcc);
    hipLaunchKernelGGL(fin_kernel, dim3(1), dim3(1), 0, stream, lossAcc, out);
}

// Round 6
// 34099.991 us; speedup vs baseline: 1.1111x; 1.1111x over previous
//
#include <hip/hip_runtime.h>
#include <math.h>

#define BSZ   384
#define BM1   383
#define DIM   256
#define NZTOT 768
#define NBLK  192
#define RPB   2
#define TPB   384
#define NITER 100
#define RINGD 8
#define NREG  288              // KK rows 0..287 live in VGPRs
#define NPAIR 48               // KK rows 288..383 live in LDS as 48 float2-pairs
#define DYNB  (NPAIR * 384 * 8)   // 147456 B dynamic LDS

// ---- ws layout (float offsets) ----
#define OFF_Z    0          // 768*256
#define OFF_NRM  196608     // 768
#define OFF_K    197376     // 384*768
#define OFF_KP   492288     // 384*384 packed KK
#define OFF_A    639744     // 384*383 final alpha
#define OFF_NUM  786816     // NITER (pad 128)
#define OFF_DEN  786944
#define OFF_ARR  787072
#define OFF_LOSS 787200     // 2 doubles

__global__ void init_kernel(float* num, float* den, int* arr, double* lossAcc) {
    int t = threadIdx.x;
    if (t < NITER) { num[t] = 0.f; den[t] = 0.f; arr[t] = 0; }
    if (t < 2) lossAcc[t] = 0.0;
}

__global__ void __launch_bounds__(64)
norm_kernel(const float* __restrict__ xis, const float* __restrict__ xjs,
            float* __restrict__ Z, float* __restrict__ nrm2) {
    const int row  = blockIdx.x;
    const int lane = threadIdx.x;
    const float* src = (row < BSZ) ? (xis + (size_t)row * DIM)
                                   : (xjs + (size_t)(row - BSZ) * DIM);
    float4 x = reinterpret_cast<const float4*>(src)[lane];
    float s = x.x*x.x + x.y*x.y + x.z*x.z + x.w*x.w;
    for (int m = 32; m; m >>= 1) s += __shfl_xor(s, m, 64);
    float nrm = sqrtf(s);
    float4 z;
    z.x = x.x / nrm; z.y = x.y / nrm; z.z = x.z / nrm; z.w = x.w / nrm;
    reinterpret_cast<float4*>(Z + (size_t)row * DIM)[lane] = z;
    float s2 = z.x*z.x + z.y*z.y + z.z*z.z + z.w*z.w;
    for (int m = 32; m; m >>= 1) s2 += __shfl_xor(s2, m, 64);
    if (lane == 0) nrm2[row] = s2;
}

__global__ void __launch_bounds__(256)
k_kernel(const float* __restrict__ Z, const float* __restrict__ nrm2,
         float* __restrict__ Km, float* __restrict__ KKp) {
    const int i = blockIdx.x;
    const int j = blockIdx.y * 256 + threadIdx.x;
    __shared__ float zi[DIM];
    zi[threadIdx.x] = Z[(size_t)i * DIM + threadIdx.x];
    __syncthreads();
    const float4* zr = reinterpret_cast<const float4*>(Z + (size_t)j * DIM);
    float acc = 0.f;
    #pragma unroll 8
    for (int k = 0; k < DIM/4; ++k) {
        float4 v = zr[k];
        acc = fmaf(zi[4*k+0], v.x, acc);
        acc = fmaf(zi[4*k+1], v.y, acc);
        acc = fmaf(zi[4*k+2], v.z, acc);
        acc = fmaf(zi[4*k+3], v.w, acc);
    }
    float sq = nrm2[i] + nrm2[j] - 2.f * acc;
    sq = fmaxf(sq, 0.f);
    const float val = expf(-0.1f * sq);
    Km[(size_t)i * NZTOT + j] = val;
    if (j < BSZ) KKp[(size_t)i * BSZ + j] = val;
}

__global__ void __launch_bounds__(TPB, 1)
pgd_kernel(const float* __restrict__ Km, const float* __restrict__ KKp,
           const float* __restrict__ alpha_init,
           float* __restrict__ afin, float* num, float* den, int* arr) {
    const int g    = blockIdx.x;     // 0..191
    const int c    = threadIdx.x;    // column 0..383
    const int lane = c & 63;
    const int wv   = c >> 6;

    extern __shared__ char dynlds[];
    float2* const klds = (float2*)dynlds;     // [NPAIR][384]

    __shared__ float4 zrow4[RPB][98];         // 392 floats/row
    __shared__ float  rscr[6][8];
    __shared__ float  rscr2[6];
    __shared__ float  SD[8];                  // 0..1 S_r, 2..3 D_r, 4 den
    __shared__ unsigned long long scanm[2];

    // ---- per-row init (column indexing; diagonal thread c==b inert) ----
    float a[RPB], p[RPB], kb[RPB];
    int   bb[RPB]; bool vld[RPB];
    #pragma unroll
    for (int r = 0; r < RPB; ++r) {
        const int b = g * RPB + r;
        bb[r]  = b;
        vld[r] = (c != b);
        kb[r]  = Km[(size_t)b * NZTOT + c];
        float v = 0.f;
        if (vld[r]) {
            const int i = c - (c > b ? 1 : 0);
            v = alpha_init[(size_t)b * BM1 + i];
            v = fminf(fmaxf(v, 0.f), 1.f);
        }
        a[r] = v; p[r] = v;
    }
    float hist[RINGD][RPB];
    #pragma unroll
    for (int s = 0; s < RINGD; ++s)
        #pragma unroll
        for (int r = 0; r < RPB; ++r) hist[s][r] = a[r];

    // ---- prologue: K becomes resident (once) ----
    float kk[NREG];
    #pragma unroll
    for (int j = 0; j < NREG; ++j) kk[j] = KKp[(size_t)j * BSZ + c];
    #pragma unroll
    for (int jj = 0; jj < NPAIR; ++jj) {
        const float x = KKp[(size_t)(NREG + 2*jj    ) * BSZ + c];
        const float y = KKp[(size_t)(NREG + 2*jj + 1) * BSZ + c];
        klds[jj * 384 + c] = make_float2(x, y);
    }
    __syncthreads();

    int stopT = -1;

    for (int t = 0; t < NITER; ++t) {
        // ---- phase 1: z build + S, D, den partials ----
        const float beta = (float)t / ((float)t + 3.0f);
        float z[RPB]; float vv[5]; float denp = 0.f;
        #pragma unroll
        for (int r = 0; r < RPB; ++r) {
            const float zr = a[r] + beta * (a[r] - p[r]);   // 0 on diagonal thread
            z[r] = zr;
            ((float*)&zrow4[r][0])[c] = zr;
            vv[r]     = zr;
            vv[2 + r] = kb[r] * zr;
            denp += a[r] * a[r];
        }
        vv[4] = denp;
        #pragma unroll
        for (int k = 0; k < 5; ++k) {
            float x = vv[k];
            x += __shfl_down(x, 32, 64); x += __shfl_down(x, 16, 64);
            x += __shfl_down(x,  8, 64); x += __shfl_down(x,  4, 64);
            x += __shfl_down(x,  2, 64); x += __shfl_down(x,  1, 64);
            if (lane == 0) rscr[wv][k] = x;
        }

        // ---- spin-free stop scan: thread tau checks iteration tau ----
        int ok = 0;
        if (c < NITER) {
            const int av = __hip_atomic_load(&arr[c], __ATOMIC_ACQUIRE, __HIP_MEMORY_SCOPE_AGENT);
            if (av == NBLK) {
                const float nn = __hip_atomic_load(&num[c], __ATOMIC_RELAXED, __HIP_MEMORY_SCOPE_AGENT);
                const float dd = __hip_atomic_load(&den[c], __ATOMIC_RELAXED, __HIP_MEMORY_SCOPE_AGENT);
                ok = (sqrtf(nn) / (sqrtf(dd) + 1e-8f) < 0.01f) ? 1 : 0;
            }
        }
        {
            const unsigned long long bm = __ballot(ok);
            if (lane == 0 && wv < 2) scanm[wv] = bm;
        }
        __syncthreads();   // B1
        {
            const unsigned long long m0 = scanm[0], m1 = scanm[1];
            const int st = m0 ? (__ffsll(m0) - 1) : (m1 ? 63 + __ffsll(m1) : -1);
            if (st >= 0) { stopT = st; break; }   // uniform across block
        }
        if (c < 5) {
            float s = 0.f;
            #pragma unroll
            for (int w = 0; w < 6; ++w) s += rscr[w][c];
            SD[c] = s;
        }

        // ---- phase 2: fully-resident matvec (no global traffic) ----
        float a00 = 0.f, a01 = 0.f, a10 = 0.f, a11 = 0.f;
        #pragma unroll
        for (int j4 = 0; j4 < NREG/4; ++j4) {
            const float4 z0 = zrow4[0][j4];
            const float4 z1 = zrow4[1][j4];
            a00 = fmaf(kk[4*j4+0], z0.x, a00);
            a01 = fmaf(kk[4*j4+1], z0.y, a01);
            a00 = fmaf(kk[4*j4+2], z0.z, a00);
            a01 = fmaf(kk[4*j4+3], z0.w, a01);
            a10 = fmaf(kk[4*j4+0], z1.x, a10);
            a11 = fmaf(kk[4*j4+1], z1.y, a11);
            a10 = fmaf(kk[4*j4+2], z1.z, a10);
            a11 = fmaf(kk[4*j4+3], z1.w, a11);
        }
        #pragma unroll
        for (int j4 = NREG/4; j4 < 96; ++j4) {
            const float4 z0 = zrow4[0][j4];
            const float4 z1 = zrow4[1][j4];
            const int pj = (j4 - NREG/4) * 2;
            const float2 kA = klds[(pj    ) * 384 + c];
            const float2 kB = klds[(pj + 1) * 384 + c];
            a00 = fmaf(kA.x, z0.x, a00);
            a01 = fmaf(kA.y, z0.y, a01);
            a00 = fmaf(kB.x, z0.z, a00);
            a01 = fmaf(kB.y, z0.w, a01);
            a10 = fmaf(kA.x, z1.x, a10);
            a11 = fmaf(kA.y, z1.y, a11);
            a10 = fmaf(kB.x, z1.z, a10);
            a11 = fmaf(kB.y, z1.w, a11);
        }
        __syncthreads();   // B2 (zrow free; SD visible)

        // ---- phase 3: grad, clipped step, reg-ring, num partial ----
        const float wr[RPB] = { a00 + a01, a10 + a11 };
        float nump = 0.f;
        const int s = t & (RINGD - 1);
        #pragma unroll
        for (int r = 0; r < RPB; ++r) {
            float an = 0.f;
            if (vld[r]) {
                const float grad = SD[r] * (1.f - kb[r]) + 0.1f * z[r] + wr[r] - SD[2 + r] - 2.0f;
                an = z[r] - 0.001f * grad;
                an = fminf(fmaxf(an, 0.f), 1.f);
            }
            const float d = an - a[r];
            nump += d * d;
            #pragma unroll
            for (int s2 = 0; s2 < RINGD; ++s2) hist[s2][r] = (s2 == s) ? an : hist[s2][r];
            p[r] = a[r]; a[r] = an;
        }
        {
            float x = nump;
            x += __shfl_down(x, 32, 64); x += __shfl_down(x, 16, 64);
            x += __shfl_down(x,  8, 64); x += __shfl_down(x,  4, 64);
            x += __shfl_down(x,  2, 64); x += __shfl_down(x,  1, 64);
            if (lane == 0) rscr2[wv] = x;
        }
        __syncthreads();   // B3
        if (c == 0) {
            const float nb = rscr2[0] + rscr2[1] + rscr2[2] + rscr2[3] + rscr2[4] + rscr2[5];
            __hip_atomic_fetch_add(&num[t], nb, __ATOMIC_RELAXED, __HIP_MEMORY_SCOPE_AGENT);
            __hip_atomic_fetch_add(&den[t], SD[4], __ATOMIC_RELAXED, __HIP_MEMORY_SCOPE_AGENT);
            __hip_atomic_fetch_add(&arr[t], 1, __ATOMIC_RELEASE, __HIP_MEMORY_SCOPE_AGENT);
        }
    }

    // ---- finalize ----
    float av[RPB];
    #pragma unroll
    for (int r = 0; r < RPB; ++r) av[r] = a[r];
    if (stopT >= 0) {
        const int s = stopT & (RINGD - 1);
        #pragma unroll
        for (int s2 = 0; s2 < RINGD; ++s2)
            #pragma unroll
            for (int r = 0; r < RPB; ++r)
                av[r] = (s2 == s) ? hist[s2][r] : av[r];
    }
    #pragma unroll
    for (int r = 0; r < RPB; ++r) {
        if (vld[r]) {
            const int i = c - (c > bb[r] ? 1 : 0);
            afin[(size_t)bb[r] * BM1 + i] = av[r];
        }
    }
}

__global__ void __launch_bounds__(TPB)
loss_kernel(const float* __restrict__ Km, const float* __restrict__ afin,
            double* lossAcc) {
    const int b    = blockIdx.x;
    const int tid  = threadIdx.x;
    const int lane = tid & 63;
    const int wv   = tid >> 6;
    __shared__ double dscr[6][2];
    double np = 0.0, pp = 0.0;
    if (tid < BM1) {
        const float ay = afin[(size_t)b * BM1 + tid];
        const int   I  = tid + (tid >= b);
        np = (double)ay * (double)Km[(size_t)I * NZTOT + BSZ + b];
        pp = (double)ay * (double)Km[(size_t)b * NZTOT + BSZ + b];
    }
    for (int o = 32; o; o >>= 1) { np += __shfl_down(np, o, 64); pp += __shfl_down(pp, o, 64); }
    if (lane == 0) { dscr[wv][0] = np; dscr[wv][1] = pp; }
    __syncthreads();
    if (tid == 0) {
        double nb = 0.0, pb = 0.0;
        for (int w = 0; w < 6; ++w) { nb += dscr[w][0]; pb += dscr[w][1]; }
        __hip_atomic_fetch_add(&lossAcc[0], nb, __ATOMIC_RELAXED, __HIP_MEMORY_SCOPE_AGENT);
        __hip_atomic_fetch_add(&lossAcc[1], pb, __ATOMIC_RELAXED, __HIP_MEMORY_SCOPE_AGENT);
    }
}

__global__ void fin_kernel(const double* lossAcc, float* out) {
    out[0] = expf((float)(lossAcc[0] / 384.0 - lossAcc[1] / 384.0));
}

extern "C" void kernel_launch(void* const* d_in, const int* in_sizes, int n_in,
                              void* d_out, int out_size, void* d_ws, size_t ws_size,
                              hipStream_t stream) {
    const float* xis        = (const float*)d_in[0];
    const float* xjs        = (const float*)d_in[1];
    const float* alpha_init = (const float*)d_in[2];
    float* ws   = (float*)d_ws;
    float* Z    = ws + OFF_Z;
    float* nrm2 = ws + OFF_NRM;
    float* Km   = ws + OFF_K;
    float* KKp  = ws + OFF_KP;
    float* afin = ws + OFF_A;
    float* num  = ws + OFF_NUM;
    float* den  = ws + OFF_DEN;
    int*   arr  = (int*)(ws + OFF_ARR);
    double* lossAcc = (double*)(ws + OFF_LOSS);
    float* out  = (float*)d_out;

    hipFuncSetAttribute((const void*)pgd_kernel,
                        hipFuncAttributeMaxDynamicSharedMemorySize, DYNB);

    hipLaunchKernelGGL(init_kernel, dim3(1), dim3(128), 0, stream, num, den, arr, lossAcc);
    hipLaunchKernelGGL(norm_kernel, dim3(NZTOT), dim3(64), 0, stream, xis, xjs, Z, nrm2);
    hipLaunchKernelGGL(k_kernel, dim3(BSZ, 3), dim3(256), 0, stream, Z, nrm2, Km, KKp);
    hipLaunchKernelGGL(pgd_kernel, dim3(NBLK), dim3(TPB), DYNB, stream,
                       Km, KKp, alpha_init, afin, num, den, arr);
    hipLaunchKernelGGL(loss_kernel, dim3(BSZ), dim3(TPB), 0, stream, Km, afin, lossAcc);
    hipLaunchKernelGGL(fin_kernel, dim3(1), dim3(1), 0, stream, lossAcc, out);
}